// Round 7
// baseline (278.820 us; speedup 1.0000x reference)
//
#include <hip/hip_runtime.h>
#include <hip/hip_bf16.h>
#include <stdint.h>

typedef __attribute__((ext_vector_type(8))) short bf16x8;
typedef __attribute__((ext_vector_type(4))) float f32x4;

#define MFMA16(a, b, c) __builtin_amdgcn_mfma_f32_16x16x32_bf16((a), (b), (c), 0, 0, 0)

// fp32 -> bf16 round-to-nearest-even
__device__ __forceinline__ unsigned short f2bf(float f) {
    union { float f; uint32_t u; } c; c.f = f;
    uint32_t u = c.u + 0x7fffu + ((c.u >> 16) & 1u);
    return (unsigned short)(u >> 16);
}

// async global->LDS, 16B/lane. LDS dest = wave-uniform base + lane*16 (linear);
// global source is per-lane (pre-swizzled). Guide §5 / rule 21.
__device__ __forceinline__ void gll16(const void* g, void* l) {
    __builtin_amdgcn_global_load_lds((const __attribute__((address_space(1))) void*)g,
                                     (__attribute__((address_space(3))) void*)l, 16, 0, 0);
}

// ---------------------------------------------------------------------------
// Weight transpose + convert: W [512][512] f32 (k-major) -> WT [n][k] bf16
// ---------------------------------------------------------------------------
__global__ void wtrans_kernel(const float* __restrict__ Wq, const float* __restrict__ Wk,
                              const float* __restrict__ Wv,
                              unsigned short* __restrict__ WqT, unsigned short* __restrict__ WkT,
                              unsigned short* __restrict__ WvT) {
    __shared__ float tile[32][33];
    const int z = blockIdx.z;
    const float* W = (z == 0) ? Wq : ((z == 1) ? Wk : Wv);
    unsigned short* WT = (z == 0) ? WqT : ((z == 1) ? WkT : WvT);
    const int k0 = blockIdx.x * 32, n0 = blockIdx.y * 32;
    const int tx = threadIdx.x, ty = threadIdx.y;
#pragma unroll
    for (int i = ty; i < 32; i += 8)
        tile[i][tx] = W[(size_t)(k0 + i) * 512 + n0 + tx];
    __syncthreads();
#pragma unroll
    for (int i = ty; i < 32; i += 8)
        WT[(size_t)(n0 + i) * 512 + k0 + tx] = f2bf(tile[tx][i]);
}

// ---------------------------------------------------------------------------
// Projection GEMM: tile M=64 x N=256, BK=64, 512 thr. z: 0->Q, 1->K, 2->Vt.
// Round-7 change: X prefetch 2-deep (3-reg rotation x0/x1/x2), issue order
// W(s+1) then X(s+2), FIFO-derived waits: s0=6, s1..5=8, s6=6, s7=0.
// X(s) retires exactly at its consuming step (2-step HBM latency cover);
// W keeps 1-step (L2-resident).
// ---------------------------------------------------------------------------
__global__ __launch_bounds__(512) void proj_kernel(
        const float* __restrict__ x1, const float* __restrict__ x2,
        const unsigned short* __restrict__ WqT, const unsigned short* __restrict__ WkT,
        const unsigned short* __restrict__ WvT,
        const float* __restrict__ bq, const float* __restrict__ bk, const float* __restrict__ bv,
        unsigned short* __restrict__ Qb, unsigned short* __restrict__ Kb,
        unsigned short* __restrict__ Vtb) {
    extern __shared__ __align__(16) char psm[];
    const int z = blockIdx.z;
    const float* X = (z == 0) ? x1 : x2;
    const unsigned short* WT = (z == 0) ? WqT : ((z == 1) ? WkT : WvT);
    const float* bias = (z == 0) ? bq : ((z == 1) ? bk : bv);

    const int tid = threadIdx.x, w = tid >> 6, lane = tid & 63;
    const int l15 = lane & 15, g = lane >> 4;
    const int mb = blockIdx.x * 64, nb = blockIdx.y * 256;

    const int xm = tid >> 3, xk8 = (tid & 7) * 8;
    const int awcol = ((tid & 7) * 16) ^ (((tid >> 3) & 7) << 4);
    const int wcol = ((lane & 7) * 16) ^ (((lane >> 3) & 7) << 4);
    const int l7x16 = (l15 & 7) << 4;

    const float* Xrow = X + (size_t)(mb + xm) * 512 + xk8;
    const char* Wbase = (const char*)WT + (size_t)(nb + (lane >> 3)) * 1024 + wcol;

    f32x4 acc[4][2] = {};
    float4 x0[2], x1r[2], x2r[2];

    // prologue: X(0)->x0, X(1)->x1r, W(0)->B0   (FIFO: X0,X1,W0)
    x0[0] = *(const float4*)(Xrow);
    x0[1] = *(const float4*)(Xrow + 4);
    x1r[0] = *(const float4*)(Xrow + 64);
    x1r[1] = *(const float4*)(Xrow + 68);
#pragma unroll
    for (int c = 0; c < 4; ++c)
        gll16(Wbase + (size_t)(w * 32 + c * 8) * 1024,
              psm + 16384 + (w * 32 + c * 8) * 128);

#define PROJ_STEP(KT, XC, XN2, AOFF, BOFF, BNOFF, WAITN, DO_W, DO_X)           \
    {                                                                          \
        if (DO_W) {                                                            \
            _Pragma("unroll")                                                  \
            for (int c = 0; c < 4; ++c)                                        \
                gll16(Wbase + ((KT) + 1) * 128 + (size_t)(w * 32 + c * 8) * 1024, \
                      psm + (BNOFF) + (w * 32 + c * 8) * 128);                 \
        }                                                                      \
        if (DO_X) {                                                            \
            const float* xs = Xrow + ((KT) + 2) * 64;                          \
            XN2[0] = *(const float4*)xs;                                       \
            XN2[1] = *(const float4*)(xs + 4);                                 \
        }                                                                      \
        asm volatile("s_waitcnt vmcnt(" #WAITN ")" ::: "memory");              \
        {                                                                      \
            uint32_t p0 = f2bf(XC[0].x) | ((uint32_t)f2bf(XC[0].y) << 16);     \
            uint32_t p1 = f2bf(XC[0].z) | ((uint32_t)f2bf(XC[0].w) << 16);     \
            uint32_t p2 = f2bf(XC[1].x) | ((uint32_t)f2bf(XC[1].y) << 16);     \
            uint32_t p3 = f2bf(XC[1].z) | ((uint32_t)f2bf(XC[1].w) << 16);     \
            int4 av; av.x = p0; av.y = p1; av.z = p2; av.w = p3;               \
            *(int4*)(psm + (AOFF) + xm * 128 + awcol) = av;                    \
        }                                                                      \
        asm volatile("s_waitcnt lgkmcnt(0)" ::: "memory");                     \
        __builtin_amdgcn_sched_barrier(0);                                     \
        __builtin_amdgcn_s_barrier();                                          \
        __builtin_amdgcn_sched_barrier(0);                                     \
        _Pragma("unroll")                                                      \
        for (int ks = 0; ks < 2; ++ks) {                                       \
            bf16x8 af[4], bfr[2];                                              \
            _Pragma("unroll")                                                  \
            for (int rb = 0; rb < 4; ++rb)                                     \
                af[rb] = *(const bf16x8*)(psm + (AOFF) + (rb * 16 + l15) * 128 \
                                          + ((ks * 64 + g * 16) ^ l7x16));     \
            _Pragma("unroll")                                                  \
            for (int cb = 0; cb < 2; ++cb)                                     \
                bfr[cb] = *(const bf16x8*)(psm + (BOFF)                        \
                           + (w * 32 + cb * 16 + l15) * 128                    \
                           + ((ks * 64 + g * 16) ^ l7x16));                    \
            _Pragma("unroll")                                                  \
            for (int rb = 0; rb < 4; ++rb)                                     \
                _Pragma("unroll")                                              \
                for (int cb = 0; cb < 2; ++cb)                                 \
                    acc[rb][cb] = MFMA16(af[rb], bfr[cb], acc[rb][cb]);        \
        }                                                                      \
        __builtin_amdgcn_sched_barrier(0);                                     \
        __builtin_amdgcn_s_barrier();                                          \
        __builtin_amdgcn_sched_barrier(0);                                     \
    }

    PROJ_STEP(0, x0,  x2r, 0,    16384, 49152, 6, 1, 1)
    PROJ_STEP(1, x1r, x0,  8192, 49152, 16384, 8, 1, 1)
    PROJ_STEP(2, x2r, x1r, 0,    16384, 49152, 8, 1, 1)
    PROJ_STEP(3, x0,  x2r, 8192, 49152, 16384, 8, 1, 1)
    PROJ_STEP(4, x1r, x0,  0,    16384, 49152, 8, 1, 1)
    PROJ_STEP(5, x2r, x1r, 8192, 49152, 16384, 8, 1, 1)
    PROJ_STEP(6, x0,  x2r, 0,    16384, 49152, 6, 1, 0)
    PROJ_STEP(7, x1r, x0,  8192, 49152, 16384, 0, 0, 0)
#undef PROJ_STEP

    if (z < 2) {
        unsigned short* O = (z == 0) ? Qb : Kb;
#pragma unroll
        for (int cb = 0; cb < 2; ++cb) {
            const int n = nb + w * 32 + cb * 16 + l15;
            const float bn = bias[n];
#pragma unroll
            for (int rb = 0; rb < 4; ++rb)
#pragma unroll
                for (int r = 0; r < 4; ++r)
                    O[(size_t)(mb + rb * 16 + g * 4 + r) * 512 + n] =
                        f2bf(acc[rb][cb][r] + bn);
        }
    } else {
        char* Tr = psm;
#pragma unroll
        for (int cb = 0; cb < 2; ++cb) {
            const int nl = w * 32 + cb * 16 + l15;
            const float bn = bias[nb + nl];
#pragma unroll
            for (int rb = 0; rb < 4; ++rb)
#pragma unroll
                for (int r = 0; r < 4; ++r) {
                    const int m2 = (rb * 16 + g * 4 + r) * 2;
                    *(unsigned short*)(Tr + nl * 128 + (m2 ^ l7x16)) =
                        f2bf(acc[rb][cb][r] + bn);
                }
        }
        asm volatile("s_waitcnt lgkmcnt(0)" ::: "memory");
        __builtin_amdgcn_sched_barrier(0);
        __builtin_amdgcn_s_barrier();
        __builtin_amdgcn_sched_barrier(0);
        const int bidx = mb >> 11, kv0 = mb & 2047;
#pragma unroll
        for (int it = 0; it < 4; ++it) {
            const int idx = it * 512 + tid;
            const int n2 = idx >> 3, t8 = idx & 7;
            int4 v = *(const int4*)(Tr + n2 * 128 + ((t8 * 16) ^ ((n2 & 7) << 4)));
            *(int4*)(Vtb + ((size_t)bidx * 512 + nb + n2) * 2048 + kv0 + t8 * 8) = v;
        }
    }
}

// ---------------------------------------------------------------------------
// Flash attention, fixed-max softmax. Block = (batch, 64 q-rows), 512 thr,
// 8 waves. Wave w = (rb=w>>1, h=w&1): S rows rb*16..+16, k-cols h*32..+32.
// Round-7 changes vs round-6 (105us, LDS-bound):
//   - V in REGISTERS (vreg[2][4], 32 VGPR; V rows wave-private -> LDS staging
//     was pure overhead): LDS/iter 520 -> 392 KB.
//   - K double-buffered (2 x 64KB in freed LDS) -> 2 barriers/iter (was 3);
//     K(kt+1) staged a full iteration early.
//   - FIFO-counted waits: top vmcnt(8) retires K(kt), keeps V(kt) in flight;
//     pre-PV vmcnt(8) retires V(kt), keeps K(kt+1) in flight.
// LDS (dyn 139776): K0 @0, K1 @65536 (each [64][1024B]) | P @131072
// [64][128B] | lred @139264. XOR swizzles (row&7)<<4 (verified rounds 4-6).
// Grid (8 batch, 32 qb): wg id = b + 8*qb -> XCD = b (K+Vt = 4MB pinned in L2).
// ---------------------------------------------------------------------------
#define ATTN_SCALE 0.04419417382415922f  // 1/sqrt(512)
#define ATTN_LDS_BYTES 139776

__global__ __attribute__((amdgpu_waves_per_eu(2, 2))) __launch_bounds__(512)
void attn_kernel(const unsigned short* __restrict__ Q,
                 const unsigned short* __restrict__ K,
                 const unsigned short* __restrict__ Vt,
                 float* __restrict__ out) {
    extern __shared__ __align__(16) char smem[];
    char* Ps = smem + 131072;               // [64][128B]
    float* lred = (float*)(smem + 139264);  // [2][64]

    const int tid = threadIdx.x, w = tid >> 6, lane = tid & 63;
    const int l15 = lane & 15, g = lane >> 4;
    const int b = blockIdx.x, qb0 = blockIdx.y * 64;
    const int rb = w >> 1, h = w & 1;
    const int l7x16 = (l15 & 7) << 4;

    const char* Kg = (const char*)K + (size_t)b * 2048 * 1024;   // K row = 1024B
    const char* Vg = (const char*)Vt + (size_t)b * 2097152;      // Vt row = 4096B

    // ---- prologue: stage K(0)->buf0; Q->regs; issue V(0)->regs ----
#pragma unroll
    for (int c = 0; c < 8; ++c) {
        const int r = w * 8 + c;
        gll16(Kg + (size_t)r * 1024 + ((lane * 16) ^ (c << 4)), smem + r * 1024);
    }
    bf16x8 qreg[16];
    {
        const char* qbase = (const char*)Q +
            ((size_t)b * 2048 + qb0 + rb * 16 + l15) * 1024 + g * 16;
#pragma unroll
        for (int dk = 0; dk < 16; ++dk)
            qreg[dk] = *(const bf16x8*)(qbase + dk * 64);
    }
    // V fragment loads: lane(l15,g) -> dv = w*64+dvb*16+l15, 16B at kv g*16
    bf16x8 vreg[2][4];
    const char* Vlane = Vg + (size_t)(w * 64 + l15) * 4096 + g * 16;
#pragma unroll
    for (int ks2 = 0; ks2 < 2; ++ks2)
#pragma unroll
        for (int dvb = 0; dvb < 4; ++dvb)
            vreg[ks2][dvb] = *(const bf16x8*)(Vlane + dvb * 65536 + ks2 * 64);

    f32x4 acc[4][4] = {};
    float lsum[4] = {0.f, 0.f, 0.f, 0.f};

    for (int kt = 0; kt < 32; ++kt) {
        // B_top: retire K(kt) gll16s (8 oldest); V(kt) reg-loads stay in flight
        asm volatile("s_waitcnt vmcnt(8)" ::: "memory");
        asm volatile("s_waitcnt lgkmcnt(0)" ::: "memory");
        __builtin_amdgcn_sched_barrier(0);
        __builtin_amdgcn_s_barrier();
        __builtin_amdgcn_sched_barrier(0);

        const char* kbuf = smem + (size_t)(kt & 1) * 65536;

        // stage K(kt+1) -> other buffer (in flight across both barriers)
        if (kt < 31) {
            char* kb = smem + (size_t)((kt + 1) & 1) * 65536;
            const char* kg = Kg + (size_t)(kt + 1) * 65536;
#pragma unroll
            for (int c = 0; c < 8; ++c) {
                const int r = w * 8 + c;
                gll16(kg + (size_t)r * 1024 + ((lane * 16) ^ (c << 4)), kb + r * 1024);
            }
        }

        // ---- QK^T: 16 qreg x 2 K-frags = 32 MFMA ----
        const char* kbr0 = kbuf + (size_t)(h * 32 + l15) * 1024;
        const char* kbr1 = kbr0 + 16 * 1024;
        f32x4 s0 = {}, s1 = {};
#pragma unroll
        for (int dk = 0; dk < 16; ++dk) {
            const int off = (dk * 64 + g * 16) ^ l7x16;
            bf16x8 kf0 = *(const bf16x8*)(kbr0 + off);
            bf16x8 kf1 = *(const bf16x8*)(kbr1 + off);
            s0 = MFMA16(qreg[dk], kf0, s0);
            s1 = MFMA16(qreg[dk], kf1, s1);
        }

        // ---- softmax (fixed max): p = exp(s*scale); P bf16 -> LDS ----
#pragma unroll
        for (int r = 0; r < 4; ++r) {
            const float p0 = __expf(s0[r] * ATTN_SCALE);
            const float p1 = __expf(s1[r] * ATTN_SCALE);
            lsum[r] += p0 + p1;
            const int q = rb * 16 + g * 4 + r;
            const int xk = (q & 7) << 4;
            const int c0 = (h * 32 + l15) * 2;
            *(unsigned short*)(Ps + q * 128 + (c0 ^ xk)) = f2bf(p0);
            *(unsigned short*)(Ps + q * 128 + ((c0 + 32) ^ xk)) = f2bf(p1);
        }

        // B3: retire V(kt) (8 older); K(kt+1) (8 newer) stays in flight. P visible.
        if (kt < 31) {
            asm volatile("s_waitcnt vmcnt(8)" ::: "memory");
        } else {
            asm volatile("s_waitcnt vmcnt(0)" ::: "memory");
        }
        asm volatile("s_waitcnt lgkmcnt(0)" ::: "memory");
        __builtin_amdgcn_sched_barrier(0);
        __builtin_amdgcn_s_barrier();
        __builtin_amdgcn_sched_barrier(0);

        // ---- PV: O[64 q][w's 64 dv] += P[64][64] * V(regs) (32 MFMA) ----
#pragma unroll
        for (int ks2 = 0; ks2 < 2; ++ks2) {
            const int off2 = (ks2 * 64 + g * 16) ^ l7x16;
            bf16x8 pa[4];
#pragma unroll
            for (int qb = 0; qb < 4; ++qb)
                pa[qb] = *(const bf16x8*)(Ps + (size_t)(qb * 16 + l15) * 128 + off2);
#pragma unroll
            for (int dvb = 0; dvb < 4; ++dvb)
#pragma unroll
                for (int qb = 0; qb < 4; ++qb)
                    acc[qb][dvb] = MFMA16(pa[qb], vreg[ks2][dvb], acc[qb][dvb]);
        }

        // issue V(kt+1) reg loads (after PV reads; before next top vmcnt)
        if (kt < 31) {
            const char* vn = Vlane + (size_t)(kt + 1) * 128;
#pragma unroll
            for (int ks2 = 0; ks2 < 2; ++ks2)
#pragma unroll
                for (int dvb = 0; dvb < 4; ++dvb)
                    vreg[ks2][dvb] = *(const bf16x8*)(vn + dvb * 65536 + ks2 * 64);
        }
    }

    // ---- l: 16-lane shuffle, cross-wave via LDS ----
#pragma unroll
    for (int r = 0; r < 4; ++r) {
        float v = lsum[r];
        v += __shfl_xor(v, 1); v += __shfl_xor(v, 2);
        v += __shfl_xor(v, 4); v += __shfl_xor(v, 8);
        lsum[r] = v;
    }
    if (l15 == 0) {
#pragma unroll
        for (int r = 0; r < 4; ++r)
            lred[h * 64 + rb * 16 + g * 4 + r] = lsum[r];
    }
    __syncthreads();

    // ---- epilogue: O = acc / l ----
    float* outb = out + ((size_t)b * 2048 + qb0) * 512 + w * 64;
#pragma unroll
    for (int qb = 0; qb < 4; ++qb)
#pragma unroll
        for (int r = 0; r < 4; ++r) {
            const int q = qb * 16 + g * 4 + r;
            const float linv = 1.0f / (lred[q] + lred[64 + q]);
#pragma unroll
            for (int dvb = 0; dvb < 4; ++dvb)
                outb[(size_t)q * 512 + dvb * 16 + l15] = acc[qb][dvb][r] * linv;
        }
}

// ---------------------------------------------------------------------------
extern "C" void kernel_launch(void* const* d_in, const int* in_sizes, int n_in,
                              void* d_out, int out_size, void* d_ws, size_t ws_size,
                              hipStream_t stream) {
    const float* x1 = (const float*)d_in[0];
    const float* x2 = (const float*)d_in[1];
    const float* Wq = (const float*)d_in[2];
    const float* bq = (const float*)d_in[3];
    const float* Wk = (const float*)d_in[4];
    const float* bk = (const float*)d_in[5];
    const float* Wv = (const float*)d_in[6];
    const float* bv = (const float*)d_in[7];
    float* out = (float*)d_out;

    char* ws = (char*)d_ws;
    unsigned short* Qb  = (unsigned short*)(ws);                      // 16 MB [b][l][d]
    unsigned short* Kb  = (unsigned short*)(ws + 16777216);           // 16 MB [b][l][d]
    unsigned short* Vtb = (unsigned short*)(ws + 33554432);           // 16 MB [b][dv][kv]
    unsigned short* WqT = (unsigned short*)(ws + 50331648);           // 512 KB [n][k]
    unsigned short* WkT = (unsigned short*)(ws + 50331648 + 524288);
    unsigned short* WvT = (unsigned short*)(ws + 50331648 + 1048576);

    wtrans_kernel<<<dim3(16, 16, 3), dim3(32, 8), 0, stream>>>(Wq, Wk, Wv, WqT, WkT, WvT);

    hipFuncSetAttribute((const void*)proj_kernel,
                        hipFuncAttributeMaxDynamicSharedMemorySize, 81920);
    proj_kernel<<<dim3(256, 2, 3), 512, 81920, stream>>>(x1, x2, WqT, WkT, WvT,
                                                         bq, bk, bv, Qb, Kb, Vtb);

    hipFuncSetAttribute((const void*)attn_kernel,
                        hipFuncAttributeMaxDynamicSharedMemorySize, ATTN_LDS_BYTES);
    attn_kernel<<<dim3(8, 32), 512, ATTN_LDS_BYTES, stream>>>(Qb, Kb, Vtb, out);
}

// Round 8
// 239.956 us; speedup vs baseline: 1.1620x; 1.1620x over previous
//
#include <hip/hip_runtime.h>
#include <hip/hip_bf16.h>
#include <stdint.h>

typedef __attribute__((ext_vector_type(8))) short bf16x8;
typedef __attribute__((ext_vector_type(4))) float f32x4;

#define MFMA16(a, b, c) __builtin_amdgcn_mfma_f32_16x16x32_bf16((a), (b), (c), 0, 0, 0)

// fp32 -> bf16 round-to-nearest-even
__device__ __forceinline__ unsigned short f2bf(float f) {
    union { float f; uint32_t u; } c; c.f = f;
    uint32_t u = c.u + 0x7fffu + ((c.u >> 16) & 1u);
    return (unsigned short)(u >> 16);
}

// async global->LDS, 16B/lane. LDS dest = wave-uniform base + lane*16 (linear);
// global source is per-lane (pre-swizzled). Guide §5 / rule 21.
__device__ __forceinline__ void gll16(const void* g, void* l) {
    __builtin_amdgcn_global_load_lds((const __attribute__((address_space(1))) void*)g,
                                     (__attribute__((address_space(3))) void*)l, 16, 0, 0);
}

// ---------------------------------------------------------------------------
// Weight transpose + convert: W [512][512] f32 (k-major) -> WT [n][k] bf16
// ---------------------------------------------------------------------------
__global__ void wtrans_kernel(const float* __restrict__ Wq, const float* __restrict__ Wk,
                              const float* __restrict__ Wv,
                              unsigned short* __restrict__ WqT, unsigned short* __restrict__ WkT,
                              unsigned short* __restrict__ WvT) {
    __shared__ float tile[32][33];
    const int z = blockIdx.z;
    const float* W = (z == 0) ? Wq : ((z == 1) ? Wk : Wv);
    unsigned short* WT = (z == 0) ? WqT : ((z == 1) ? WkT : WvT);
    const int k0 = blockIdx.x * 32, n0 = blockIdx.y * 32;
    const int tx = threadIdx.x, ty = threadIdx.y;
#pragma unroll
    for (int i = ty; i < 32; i += 8)
        tile[i][tx] = W[(size_t)(k0 + i) * 512 + n0 + tx];
    __syncthreads();
#pragma unroll
    for (int i = ty; i < 32; i += 8)
        WT[(size_t)(n0 + i) * 512 + k0 + tx] = f2bf(tile[tx][i]);
}

// ---------------------------------------------------------------------------
// Projection GEMM: tile M=64 x N=256, BK=64, 512 thr. z: 0->Q, 1->K, 2->Vt.
// Round-8 change: ONE barrier per step (was 2). With A and B both
// double-buffered, the post-MFMA barrier is redundant: step kt+1's writes go
// to the other buffers, and BAR(kt) already implies all waves finished
// MFMA(kt-1) (program order). Step: {vmcnt(4) [X(kt) ready]; pack+write A(kt);
// lgkm; BAR; issue X(kt+1), W(kt+1)->B-other; vmcnt(6) [W(kt) landed]; MFMA}.
// FIFO verified: X retires at its pack, W at its MFMA, every step.
// LDS (dyn 81920): A0 @0, A1 @8192 [64][128B] | B0 @16384, B1 @49152 [256][128B].
// Swizzle: LDS[row][colbyte ^ ((row&7)<<4)] both sides (verified r4-7).
// ---------------------------------------------------------------------------
__global__ __launch_bounds__(512) void proj_kernel(
        const float* __restrict__ x1, const float* __restrict__ x2,
        const unsigned short* __restrict__ WqT, const unsigned short* __restrict__ WkT,
        const unsigned short* __restrict__ WvT,
        const float* __restrict__ bq, const float* __restrict__ bk, const float* __restrict__ bv,
        unsigned short* __restrict__ Qb, unsigned short* __restrict__ Kb,
        unsigned short* __restrict__ Vtb) {
    extern __shared__ __align__(16) char psm[];
    const int z = blockIdx.z;
    const float* X = (z == 0) ? x1 : x2;
    const unsigned short* WT = (z == 0) ? WqT : ((z == 1) ? WkT : WvT);
    const float* bias = (z == 0) ? bq : ((z == 1) ? bk : bv);

    const int tid = threadIdx.x, w = tid >> 6, lane = tid & 63;
    const int l15 = lane & 15, g = lane >> 4;
    const int mb = blockIdx.x * 64, nb = blockIdx.y * 256;

    const int xm = tid >> 3, xk8 = (tid & 7) * 8;
    const int awcol = ((tid & 7) * 16) ^ (((tid >> 3) & 7) << 4);
    const int wcol = ((lane & 7) * 16) ^ (((lane >> 3) & 7) << 4);
    const int l7x16 = (l15 & 7) << 4;

    const float* Xrow = X + (size_t)(mb + xm) * 512 + xk8;
    const char* Wbase = (const char*)WT + (size_t)(nb + (lane >> 3)) * 1024 + wcol;

    f32x4 acc[4][2] = {};
    float4 xr0[2], xr1[2];

    // prologue: X(0)->xr0 (2 loads), W(0)->B0 (4 gll16). FIFO: [X0 x2, W0 x4]
    xr0[0] = *(const float4*)(Xrow);
    xr0[1] = *(const float4*)(Xrow + 4);
#pragma unroll
    for (int c = 0; c < 4; ++c)
        gll16(Wbase + (size_t)(w * 32 + c * 8) * 1024,
              psm + 16384 + (w * 32 + c * 8) * 128);

#define PROJ_STEP(KT, XC, XN, ACUR, BCUR, BNXT, LAST)                          \
    {                                                                          \
        asm volatile("s_waitcnt vmcnt(4)" ::: "memory");  /* X(KT) ready */    \
        {                                                                      \
            uint32_t p0 = f2bf(XC[0].x) | ((uint32_t)f2bf(XC[0].y) << 16);     \
            uint32_t p1 = f2bf(XC[0].z) | ((uint32_t)f2bf(XC[0].w) << 16);     \
            uint32_t p2 = f2bf(XC[1].x) | ((uint32_t)f2bf(XC[1].y) << 16);     \
            uint32_t p3 = f2bf(XC[1].z) | ((uint32_t)f2bf(XC[1].w) << 16);     \
            int4 av; av.x = p0; av.y = p1; av.z = p2; av.w = p3;               \
            *(int4*)(psm + (ACUR) + xm * 128 + awcol) = av;                    \
        }                                                                      \
        asm volatile("s_waitcnt lgkmcnt(0)" ::: "memory");                     \
        __builtin_amdgcn_sched_barrier(0);                                     \
        __builtin_amdgcn_s_barrier();                                          \
        __builtin_amdgcn_sched_barrier(0);                                     \
        if (!(LAST)) {                                                         \
            const float* xs = Xrow + ((KT) + 1) * 64;                          \
            XN[0] = *(const float4*)xs;                                        \
            XN[1] = *(const float4*)(xs + 4);                                  \
            _Pragma("unroll")                                                  \
            for (int c = 0; c < 4; ++c)                                        \
                gll16(Wbase + ((KT) + 1) * 128 + (size_t)(w * 32 + c * 8) * 1024, \
                      psm + (BNXT) + (w * 32 + c * 8) * 128);                  \
            asm volatile("s_waitcnt vmcnt(6)" ::: "memory"); /* W(KT) in LDS */\
        } else {                                                               \
            asm volatile("s_waitcnt vmcnt(0)" ::: "memory");                   \
        }                                                                      \
        _Pragma("unroll")                                                      \
        for (int ks = 0; ks < 2; ++ks) {                                       \
            bf16x8 af[4], bfr[2];                                              \
            _Pragma("unroll")                                                  \
            for (int rb = 0; rb < 4; ++rb)                                     \
                af[rb] = *(const bf16x8*)(psm + (ACUR) + (rb * 16 + l15) * 128 \
                                          + ((ks * 64 + g * 16) ^ l7x16));     \
            _Pragma("unroll")                                                  \
            for (int cb = 0; cb < 2; ++cb)                                     \
                bfr[cb] = *(const bf16x8*)(psm + (BCUR)                        \
                           + (w * 32 + cb * 16 + l15) * 128                    \
                           + ((ks * 64 + g * 16) ^ l7x16));                    \
            _Pragma("unroll")                                                  \
            for (int rb = 0; rb < 4; ++rb)                                     \
                _Pragma("unroll")                                              \
                for (int cb = 0; cb < 2; ++cb)                                 \
                    acc[rb][cb] = MFMA16(af[rb], bfr[cb], acc[rb][cb]);        \
        }                                                                      \
    }

    PROJ_STEP(0, xr0, xr1, 0,    16384, 49152, 0)
    PROJ_STEP(1, xr1, xr0, 8192, 49152, 16384, 0)
    PROJ_STEP(2, xr0, xr1, 0,    16384, 49152, 0)
    PROJ_STEP(3, xr1, xr0, 8192, 49152, 16384, 0)
    PROJ_STEP(4, xr0, xr1, 0,    16384, 49152, 0)
    PROJ_STEP(5, xr1, xr0, 8192, 49152, 16384, 0)
    PROJ_STEP(6, xr0, xr1, 0,    16384, 49152, 0)
    PROJ_STEP(7, xr1, xr0, 8192, 49152, 16384, 1)
#undef PROJ_STEP

    if (z < 2) {
        unsigned short* O = (z == 0) ? Qb : Kb;
#pragma unroll
        for (int cb = 0; cb < 2; ++cb) {
            const int n = nb + w * 32 + cb * 16 + l15;
            const float bn = bias[n];
#pragma unroll
            for (int rb = 0; rb < 4; ++rb)
#pragma unroll
                for (int r = 0; r < 4; ++r)
                    O[(size_t)(mb + rb * 16 + g * 4 + r) * 512 + n] =
                        f2bf(acc[rb][cb][r] + bn);
        }
    } else {
        // Tr overlaps A0/A1/B0 -> need a barrier first (no post-MFMA barrier
        // in the new step structure): all waves must finish step-7 LDS reads.
        __builtin_amdgcn_sched_barrier(0);
        __builtin_amdgcn_s_barrier();
        __builtin_amdgcn_sched_barrier(0);
        char* Tr = psm;
#pragma unroll
        for (int cb = 0; cb < 2; ++cb) {
            const int nl = w * 32 + cb * 16 + l15;
            const float bn = bias[nb + nl];
#pragma unroll
            for (int rb = 0; rb < 4; ++rb)
#pragma unroll
                for (int r = 0; r < 4; ++r) {
                    const int m2 = (rb * 16 + g * 4 + r) * 2;
                    *(unsigned short*)(Tr + nl * 128 + (m2 ^ l7x16)) =
                        f2bf(acc[rb][cb][r] + bn);
                }
        }
        asm volatile("s_waitcnt lgkmcnt(0)" ::: "memory");
        __builtin_amdgcn_sched_barrier(0);
        __builtin_amdgcn_s_barrier();
        __builtin_amdgcn_sched_barrier(0);
        const int bidx = mb >> 11, kv0 = mb & 2047;
#pragma unroll
        for (int it = 0; it < 4; ++it) {
            const int idx = it * 512 + tid;
            const int n2 = idx >> 3, t8 = idx & 7;
            int4 v = *(const int4*)(Tr + n2 * 128 + ((t8 * 16) ^ ((n2 & 7) << 4)));
            *(int4*)(Vtb + ((size_t)bidx * 512 + nb + n2) * 2048 + kv0 + t8 * 8) = v;
        }
    }
}

// ---------------------------------------------------------------------------
// Flash attention — EXACT round-6 kernel (verified 105 us; rounds 7's V-regs
// variant regressed to 138 and is abandoned). Fixed-max softmax. Block =
// (batch, 64 q-rows), 512 thr, 8 waves. Wave w = (rb=w>>1, h=w&1): S rows
// rb*16..+16, k-cols h*32..+32. qreg[16] = 64 VGPR.
// LDS (dyn 139776): K @0 [64][1024B] | V @65536 [512][128B] | P @131072
// [64][128B] | lred @139264. XOR swizzles (row&7)<<4.
// Per iter: vmcnt(0)+lgkm+B1 [K(kt) landed]; stage V(kt); QK; lgkm+B2;
// stage K(kt+1); exp+P-write; vmcnt(8)+lgkm+B3 [V landed, K in flight]; PV.
// Grid (8 batch, 32 qb): wg id = b + 8*qb -> XCD = b (K+Vt pinned in 4MB L2).
// ---------------------------------------------------------------------------
#define ATTN_SCALE 0.04419417382415922f  // 1/sqrt(512)
#define ATTN_LDS_BYTES 139776

__global__ __attribute__((amdgpu_waves_per_eu(2, 2))) __launch_bounds__(512)
void attn_kernel(const unsigned short* __restrict__ Q,
                 const unsigned short* __restrict__ K,
                 const unsigned short* __restrict__ Vt,
                 float* __restrict__ out) {
    extern __shared__ __align__(16) char smem[];
    char* Kb = smem;                        // [64][1024B]
    char* Vb = smem + 65536;                // [512][128B]
    char* Ps = smem + 131072;               // [64][128B]
    float* lred = (float*)(smem + 139264);  // [2][64]

    const int tid = threadIdx.x, w = tid >> 6, lane = tid & 63;
    const int l15 = lane & 15, g = lane >> 4;
    const int b = blockIdx.x, qb0 = blockIdx.y * 64;
    const int rb = w >> 1, h = w & 1;
    const int l7x16 = (l15 & 7) << 4;

    const char* Kg = (const char*)K + (size_t)b * 2048 * 1024;   // K row = 1024B
    const char* Vg = (const char*)Vt + (size_t)b * 512 * 4096;   // Vt row = 4096B
    const int vcol = ((lane & 7) * 16) ^ (((lane >> 3) & 7) << 4);
    const int vrow = lane >> 3;

    // ---- prologue: stage K(0); Q -> regs (16 rows per wave) ----
#pragma unroll
    for (int c = 0; c < 8; ++c) {
        const int r = w * 8 + c;
        gll16(Kg + (size_t)r * 1024 + ((lane * 16) ^ (c << 4)), Kb + r * 1024);
    }
    bf16x8 qreg[16];
    {
        const char* qbase = (const char*)Q +
            ((size_t)b * 2048 + qb0 + rb * 16 + l15) * 1024 + g * 16;
#pragma unroll
        for (int dk = 0; dk < 16; ++dk)
            qreg[dk] = *(const bf16x8*)(qbase + dk * 64);
    }

    f32x4 acc[4][4] = {};
    float lsum[4] = {0.f, 0.f, 0.f, 0.f};

    for (int kt = 0; kt < 32; ++kt) {
        // B1: K(kt) landed; all waves done PV(kt-1)
        asm volatile("s_waitcnt vmcnt(0)" ::: "memory");
        asm volatile("s_waitcnt lgkmcnt(0)" ::: "memory");
        __builtin_amdgcn_sched_barrier(0);
        __builtin_amdgcn_s_barrier();
        __builtin_amdgcn_sched_barrier(0);

        // stage V(kt) -> Vb (lands during QK+softmax; waited at B3 via vmcnt(8))
        {
            const char* vg = Vg + (size_t)kt * 128;
#pragma unroll
            for (int c = 0; c < 8; ++c) {
                const int r0 = w * 64 + c * 8;
                gll16(vg + (size_t)(r0 + vrow) * 4096 + vcol, Vb + r0 * 128);
            }
        }

        // ---- QK^T: 16 qreg x 2 K-frags = 32 MFMA, 32 LDS reads ----
        const char* kbr0 = Kb + (size_t)(h * 32 + l15) * 1024;
        const char* kbr1 = kbr0 + 16 * 1024;
        f32x4 s0 = {}, s1 = {};
#pragma unroll
        for (int dk = 0; dk < 16; ++dk) {
            const int off = (dk * 64 + g * 16) ^ l7x16;
            bf16x8 kf0 = *(const bf16x8*)(kbr0 + off);
            bf16x8 kf1 = *(const bf16x8*)(kbr1 + off);
            s0 = MFMA16(qreg[dk], kf0, s0);
            s1 = MFMA16(qreg[dk], kf1, s1);
        }

        // B2: all waves done reading Kb
        asm volatile("s_waitcnt lgkmcnt(0)" ::: "memory");
        __builtin_amdgcn_sched_barrier(0);
        __builtin_amdgcn_s_barrier();
        __builtin_amdgcn_sched_barrier(0);

        // stage K(kt+1) -> Kb (stays in flight across B3 into next iter)
        if (kt < 31) {
            const char* kg = Kg + (size_t)(kt + 1) * 65536;
#pragma unroll
            for (int c = 0; c < 8; ++c) {
                const int r = w * 8 + c;
                gll16(kg + (size_t)r * 1024 + ((lane * 16) ^ (c << 4)), Kb + r * 1024);
            }
        }

        // ---- softmax (fixed max): p = exp(s*scale); P bf16 -> LDS ----
#pragma unroll
        for (int r = 0; r < 4; ++r) {
            const float p0 = __expf(s0[r] * ATTN_SCALE);
            const float p1 = __expf(s1[r] * ATTN_SCALE);
            lsum[r] += p0 + p1;
            const int q = rb * 16 + g * 4 + r;
            const int xk = (q & 7) << 4;
            const int c0 = (h * 32 + l15) * 2;
            *(unsigned short*)(Ps + q * 128 + (c0 ^ xk)) = f2bf(p0);
            *(unsigned short*)(Ps + q * 128 + ((c0 + 32) ^ xk)) = f2bf(p1);
        }

        // B3: V(kt) landed (oldest 8; K(kt+1)'s 8 stay in flight), P visible
        if (kt < 31) {
            asm volatile("s_waitcnt vmcnt(8)" ::: "memory");
        } else {
            asm volatile("s_waitcnt vmcnt(0)" ::: "memory");
        }
        asm volatile("s_waitcnt lgkmcnt(0)" ::: "memory");
        __builtin_amdgcn_sched_barrier(0);
        __builtin_amdgcn_s_barrier();
        __builtin_amdgcn_sched_barrier(0);

        // ---- PV: O[64 q][w's 64 dv] += P[64][64] * V[64][64dv] (32 MFMA) ----
#pragma unroll
        for (int ks2 = 0; ks2 < 2; ++ks2) {
            const int off2 = (ks2 * 64 + g * 16) ^ l7x16;
            bf16x8 pa[4];
#pragma unroll
            for (int qb = 0; qb < 4; ++qb)
                pa[qb] = *(const bf16x8*)(Ps + (size_t)(qb * 16 + l15) * 128 + off2);
#pragma unroll
            for (int dvb = 0; dvb < 4; ++dvb) {
                bf16x8 vf = *(const bf16x8*)(Vb + (size_t)(w * 64 + dvb * 16 + l15) * 128 + off2);
#pragma unroll
                for (int qb = 0; qb < 4; ++qb)
                    acc[qb][dvb] = MFMA16(pa[qb], vf, acc[qb][dvb]);
            }
        }
    }

    asm volatile("s_waitcnt vmcnt(0)" ::: "memory");

    // ---- l: 16-lane shuffle (sum over this wave's 32 k-cols), cross-wave LDS ----
#pragma unroll
    for (int r = 0; r < 4; ++r) {
        float v = lsum[r];
        v += __shfl_xor(v, 1); v += __shfl_xor(v, 2);
        v += __shfl_xor(v, 4); v += __shfl_xor(v, 8);
        lsum[r] = v;
    }
    if (l15 == 0) {
#pragma unroll
        for (int r = 0; r < 4; ++r)
            lred[h * 64 + rb * 16 + g * 4 + r] = lsum[r];
    }
    __syncthreads();

    // ---- epilogue: O = acc / l ----
    float* outb = out + ((size_t)b * 2048 + qb0) * 512 + w * 64;
#pragma unroll
    for (int qb = 0; qb < 4; ++qb)
#pragma unroll
        for (int r = 0; r < 4; ++r) {
            const int q = qb * 16 + g * 4 + r;
            const float linv = 1.0f / (lred[q] + lred[64 + q]);
#pragma unroll
            for (int dvb = 0; dvb < 4; ++dvb)
                outb[(size_t)q * 512 + dvb * 16 + l15] = acc[qb][dvb][r] * linv;
        }
}

// ---------------------------------------------------------------------------
extern "C" void kernel_launch(void* const* d_in, const int* in_sizes, int n_in,
                              void* d_out, int out_size, void* d_ws, size_t ws_size,
                              hipStream_t stream) {
    const float* x1 = (const float*)d_in[0];
    const float* x2 = (const float*)d_in[1];
    const float* Wq = (const float*)d_in[2];
    const float* bq = (const float*)d_in[3];
    const float* Wk = (const float*)d_in[4];
    const float* bk = (const float*)d_in[5];
    const float* Wv = (const float*)d_in[6];
    const float* bv = (const float*)d_in[7];
    float* out = (float*)d_out;

    char* ws = (char*)d_ws;
    unsigned short* Qb  = (unsigned short*)(ws);                      // 16 MB [b][l][d]
    unsigned short* Kb  = (unsigned short*)(ws + 16777216);           // 16 MB [b][l][d]
    unsigned short* Vtb = (unsigned short*)(ws + 33554432);           // 16 MB [b][dv][kv]
    unsigned short* WqT = (unsigned short*)(ws + 50331648);           // 512 KB [n][k]
    unsigned short* WkT = (unsigned short*)(ws + 50331648 + 524288);
    unsigned short* WvT = (unsigned short*)(ws + 50331648 + 1048576);

    wtrans_kernel<<<dim3(16, 16, 3), dim3(32, 8), 0, stream>>>(Wq, Wk, Wv, WqT, WkT, WvT);

    hipFuncSetAttribute((const void*)proj_kernel,
                        hipFuncAttributeMaxDynamicSharedMemorySize, 81920);
    proj_kernel<<<dim3(256, 2, 3), 512, 81920, stream>>>(x1, x2, WqT, WkT, WvT,
                                                         bq, bk, bv, Qb, Kb, Vtb);

    hipFuncSetAttribute((const void*)attn_kernel,
                        hipFuncAttributeMaxDynamicSharedMemorySize, ATTN_LDS_BYTES);
    attn_kernel<<<dim3(8, 32), 512, ATTN_LDS_BYTES, stream>>>(Qb, Kb, Vtb, out);
}